// Round 7
// baseline (157.516 us; speedup 1.0000x reference)
//
#include <hip/hip_runtime.h>
#include <hip/hip_bf16.h>
#include <math.h>

#define B_  2
#define S_  2048
#define H_  16
#define D_  64

typedef __attribute__((ext_vector_type(8))) short bf16x8_t;
typedef __attribute__((ext_vector_type(4))) float f32x4_t;

__device__ __forceinline__ unsigned short f2bf(float f) {
    __hip_bfloat16 h = __float2bfloat16(f);
    return __builtin_bit_cast(unsigned short, h);
}
__device__ __forceinline__ float bf2f(unsigned short u) {
    unsigned int x = ((unsigned int)u) << 16;
    return __builtin_bit_cast(float, x);
}

// ---------------- kernel 1: prep1 — QK rotate+decay (R6-proven P1+P2) ----------
// 1024 blocks x 256 threads; 4 rows per block; qb/kb keep input layout [b][s][1024].
__global__ __launch_bounds__(256) void prep1_kernel(const float* __restrict__ Q,
                                                    const float* __restrict__ K,
                                                    unsigned short* __restrict__ qb,
                                                    unsigned short* __restrict__ kb) {
    __shared__ float4 rotq[4 * 32];
    __shared__ float  gl[4 * 16 * 2];
    int t   = threadIdx.x;
    int bid = blockIdx.x;

    if (t < 128) {
        int sl = t >> 5, i = t & 31;
        int s  = (bid * 4 + sl) & 2047;
        float pos = (float)s;
        float bsc  = (2.0f * (float)i + 25.6f) / 89.6f;
        float xsc  = exp2f(log2f(bsc) * pos * (1.0f / 512.0f));
        float invf = exp2f(-(float)i * (13.287712379549449f / 32.0f));
        float ang  = pos * invf;
        float kq = rintf(ang * 0.15915494309189535f);
        float rr = fmaf(kq, -6.2831853071795865f, ang);
        float sn = sinf(rr), cs = cosf(rr);
        float rxs = 1.0f / xsc;
        rotq[sl * 32 + i] = make_float4(cs * xsc, sn * xsc, cs * rxs, sn * rxs);
    } else {
        int u  = t - 128;
        int sl = u >> 5, hh = (u >> 1) & 15, pm = u & 1;
        int s  = (bid * 4 + sl) & 2047;
        float lnv = -3.4657359027997265f + (float)hh * (-0.18483924814931874f);
        float l2g = log2f(1.0f - expf(lnv));
        gl[(sl * 16 + hh) * 2 + pm] = exp2f((pm ? -(float)s : (float)s) * l2g);
    }
    __syncthreads();

    int hh = t >> 4, i8 = t & 15;
#pragma unroll
    for (int j = 0; j < 4; ++j) {
        int r = bid * 4 + j;
        float4 r0 = rotq[j * 32 + 2 * i8];
        float4 r1 = rotq[j * 32 + 2 * i8 + 1];
        float gx = gl[(j * 16 + hh) * 2 + 0];
        float gy = gl[(j * 16 + hh) * 2 + 1];

        long idx = (long)r * 1024 + t * 4;
        float4 xq = *(const float4*)(Q + idx);
        float4 xk = *(const float4*)(K + idx);

        float cq0 = r0.x * gx, sq0 = r0.y * gx;
        float ck0 = r0.z * gy, sk0 = r0.w * gy;
        float cq1 = r1.x * gx, sq1 = r1.y * gx;
        float ck1 = r1.z * gy, sk1 = r1.w * gy;

        float q0 = xq.x * cq0 - xq.y * sq0, q1 = xq.y * cq0 + xq.x * sq0;
        float q2 = xq.z * cq1 - xq.w * sq1, q3 = xq.w * cq1 + xq.z * sq1;
        float k0 = xk.x * ck0 - xk.y * sk0, k1 = xk.y * ck0 + xk.x * sk0;
        float k2 = xk.z * ck1 - xk.w * sk1, k3 = xk.w * ck1 + xk.z * sk1;

        *(uint2*)(qb + idx) = make_uint2((unsigned)f2bf(q0) | ((unsigned)f2bf(q1) << 16),
                                         (unsigned)f2bf(q2) | ((unsigned)f2bf(q3) << 16));
        *(uint2*)(kb + idx) = make_uint2((unsigned)f2bf(k0) | ((unsigned)f2bf(k1) << 16),
                                         (unsigned)f2bf(k2) | ((unsigned)f2bf(k3) << 16));
    }
}

// ---------------- kernel 2: prep2 — transposes (V from input fp32; K from kb bf16) ----
// blocks [0,1024):    V-tile -> vt[bh][d][s]   (verbatim proven path)
// blocks [1024,2048): K-tile -> kt[bh][d][s]   (same code, bf16 source)
__global__ __launch_bounds__(256) void prep2_kernel(const float* __restrict__ V,
                                                    const unsigned short* __restrict__ kb,
                                                    unsigned short* __restrict__ vt,
                                                    unsigned short* __restrict__ kt) {
    __shared__ float tile[64 * 65];
    int t   = threadIdx.x;
    int bid = blockIdx.x;
    bool isK = bid >= 1024;
    int vb = isK ? bid - 1024 : bid;
    int bh = vb & 31;
    int b = bh >> 4, hh = bh & 15;
    int s0 = (vb >> 5) * 64;

#pragma unroll
    for (int it = 0; it < 4; ++it) {
        int f  = it * 256 + t;
        int sl = f >> 4;
        int d4 = f & 15;
        long a = ((long)(b * S_ + s0 + sl)) * 1024 + hh * 64 + d4 * 4;
        float f0, f1, f2, f3;
        if (!isK) {
            float4 v = *(const float4*)(V + a);
            f0 = v.x; f1 = v.y; f2 = v.z; f3 = v.w;
        } else {
            uint2 u = *(const uint2*)(kb + a);
            f0 = bf2f((unsigned short)(u.x & 0xffff));
            f1 = bf2f((unsigned short)(u.x >> 16));
            f2 = bf2f((unsigned short)(u.y & 0xffff));
            f3 = bf2f((unsigned short)(u.y >> 16));
        }
        tile[sl * 65 + d4 * 4 + 0] = f0;
        tile[sl * 65 + d4 * 4 + 1] = f1;
        tile[sl * 65 + d4 * 4 + 2] = f2;
        tile[sl * 65 + d4 * 4 + 3] = f3;
    }
    __syncthreads();
    int d = t >> 2, c = t & 3;
    unsigned int pk[8];
#pragma unroll
    for (int jj = 0; jj < 8; ++jj) {
        float f0 = tile[(c * 16 + 2 * jj + 0) * 65 + d];
        float f1 = tile[(c * 16 + 2 * jj + 1) * 65 + d];
        pk[jj] = (unsigned int)f2bf(f0) | ((unsigned int)f2bf(f1) << 16);
    }
    unsigned short* outp = (isK ? kt : vt) + ((long)(bh * 64 + d)) * S_ + s0 + c * 16;
    ((uint4*)outp)[0] = make_uint4(pk[0], pk[1], pk[2], pk[3]);
    ((uint4*)outp)[1] = make_uint4(pk[4], pk[5], pk[6], pk[7]);
}

// ---------------- kernel 3: state — chunk-recurrent prefix states ----------------
// 32 blocks (one per bh) x 256 threads (4 waves; wave w owns dv rows w*16..+15).
// S^T[dv][dk] accumulated in fp32 regs across 32 chunks of 64 rows:
//   S^T += V^T_j x K^T_j   via mfma(A=V^T frag [dv, s], B=K^T frag [dk, s]).
// Before adding chunk j (j>0), writes the prefix Sg[bh][j] (bf16, [dv][64+dk]).
// Decay is already folded into kb (gamma^-s), so plain summation is exact.
__global__ __launch_bounds__(256) void state_kernel(const unsigned short* __restrict__ kt,
                                                    const unsigned short* __restrict__ vt,
                                                    unsigned short* __restrict__ Sg) {
    int t = threadIdx.x;
    int w = t >> 6, lane = t & 63, quad = lane >> 4, l16 = lane & 15;
    int bh = blockIdx.x;
    const unsigned short* ktB = kt + (long)bh * 64 * S_;
    const unsigned short* vtB = vt + (long)bh * 64 * S_;

    f32x4_t accS[4];
#pragma unroll
    for (int dkt = 0; dkt < 4; ++dkt) accS[dkt] = (f32x4_t){0.f, 0.f, 0.f, 0.f};

    for (int j = 0; j < 32; ++j) {
        if (j > 0) {
            unsigned short* Sp = Sg + ((long)(bh * 32 + j)) * 4096;
#pragma unroll
            for (int dkt = 0; dkt < 4; ++dkt)
#pragma unroll
                for (int r = 0; r < 4; ++r)
                    Sp[(w * 16 + quad * 4 + r) * 64 + dkt * 16 + l16] = f2bf(accS[dkt][r]);
        }
        bf16x8_t aV[2], bK[4][2];
#pragma unroll
        for (int sst = 0; sst < 2; ++sst)
            aV[sst] = *(const bf16x8_t*)(vtB + (long)(w * 16 + l16) * S_ + j * 64 + sst * 32 + quad * 8);
#pragma unroll
        for (int dkt = 0; dkt < 4; ++dkt)
#pragma unroll
            for (int sst = 0; sst < 2; ++sst)
                bK[dkt][sst] = *(const bf16x8_t*)(ktB + (long)(dkt * 16 + l16) * S_ + j * 64 + sst * 32 + quad * 8);
#pragma unroll
        for (int dkt = 0; dkt < 4; ++dkt)
#pragma unroll
            for (int sst = 0; sst < 2; ++sst)
                accS[dkt] = __builtin_amdgcn_mfma_f32_16x16x32_bf16(aV[sst], bK[dkt][sst], accS[dkt], 0, 0, 0);
    }
}

// ---------------- kernel 4: outc — per-(bh,chunk) output -----------------------
// 1024 blocks x 256 threads (4 independent waves, NO block barriers).
// Wave w owns q-rows w*16..+15 of the chunk:
//   cross: accO += mfma(A=q-hat frag, B=S^T frag)        (t>0)
//   diag : P' = mfma(A=k-hat frag, B=q-hat frag)  -> lane holds 4 consecutive s'
//          -> mask q>=s' -> pack -> one ds_write_b64 per strip -> PV via strip reads.
__global__ __launch_bounds__(256) void outc_kernel(const unsigned short* __restrict__ qb,
                                                   const unsigned short* __restrict__ kb,
                                                   const unsigned short* __restrict__ vt,
                                                   const unsigned short* __restrict__ Sg,
                                                   float* __restrict__ out) {
    __shared__ __align__(16) unsigned short strip[4][16 * 72];  // per-wave 16 q x 64 s' (+8 pad)
    int t = threadIdx.x;
    int w = t >> 6, lane = t & 63, quad = lane >> 4, l16 = lane & 15;
    int idx = blockIdx.x;
    int bh  = idx & 31;
    int tch = idx >> 5;           // chunk 0..31
    int b = bh >> 4, hh = bh & 15;

    const unsigned short* qB = qb + ((long)(b * S_ + tch * 64)) * 1024 + hh * 64;
    const unsigned short* kB = kb + ((long)(b * S_ + tch * 64)) * 1024 + hh * 64;
    const unsigned short* vB = vt + (long)bh * 64 * S_ + tch * 64;
    const unsigned short* SB = Sg + ((long)(bh * 32 + tch)) * 4096;

    bf16x8_t aQ[2];
#pragma unroll
    for (int kk = 0; kk < 2; ++kk)
        aQ[kk] = *(const bf16x8_t*)(qB + (long)(w * 16 + l16) * 1024 + kk * 32 + quad * 8);

    f32x4_t accO[4];
#pragma unroll
    for (int dvt = 0; dvt < 4; ++dvt) accO[dvt] = (f32x4_t){0.f, 0.f, 0.f, 0.f};

    // ---- cross-chunk: q-hat x S^T
    if (tch > 0) {
#pragma unroll
        for (int dvt = 0; dvt < 4; ++dvt)
#pragma unroll
            for (int kk = 0; kk < 2; ++kk) {
                bf16x8_t bS = *(const bf16x8_t*)(SB + (dvt * 16 + l16) * 64 + kk * 32 + quad * 8);
                accO[dvt] = __builtin_amdgcn_mfma_f32_16x16x32_bf16(aQ[kk], bS, accO[dvt], 0, 0, 0);
            }
    }

    // ---- diagonal chunk: swapped QK^T, strip, PV
    unsigned short* sw = strip[w];
    // zero strip cols for s'-tiles above this wave's q range (never computed)
    for (int st = w + 1; st < 4; ++st)
        *(uint2*)&sw[l16 * 72 + st * 16 + quad * 4] = make_uint2(0u, 0u);

    for (int st = 0; st <= w; ++st) {
        f32x4_t pp = (f32x4_t){0.f, 0.f, 0.f, 0.f};
#pragma unroll
        for (int kk = 0; kk < 2; ++kk) {
            bf16x8_t aK = *(const bf16x8_t*)(kB + (long)(st * 16 + l16) * 1024 + kk * 32 + quad * 8);
            pp = __builtin_amdgcn_mfma_f32_16x16x32_bf16(aK, aQ[kk], pp, 0, 0, 0);
        }
        // lane holds P[q = w*16+l16][s' = st*16+quad*4+r], r=0..3 consecutive
        if (st == w) {
#pragma unroll
            for (int r = 0; r < 4; ++r)
                if (quad * 4 + r > l16) pp[r] = 0.0f;   // keep iff q >= s'
        }
        uint2 pk2;
        pk2.x = (unsigned)f2bf(pp[0]) | ((unsigned)f2bf(pp[1]) << 16);
        pk2.y = (unsigned)f2bf(pp[2]) | ((unsigned)f2bf(pp[3]) << 16);
        *(uint2*)&sw[l16 * 72 + st * 16 + quad * 4] = pk2;
    }

    // PV: A = strip rows (q, k-dim s'), B = V^T rows (dv)
    bf16x8_t aP0 = *(const bf16x8_t*)&sw[l16 * 72 + 0 * 32 + quad * 8];
#pragma unroll
    for (int dvt = 0; dvt < 4; ++dvt) {
        bf16x8_t bV0 = *(const bf16x8_t*)(vB + (long)(dvt * 16 + l16) * S_ + 0 * 32 + quad * 8);
        accO[dvt] = __builtin_amdgcn_mfma_f32_16x16x32_bf16(aP0, bV0, accO[dvt], 0, 0, 0);
    }
    if (w >= 2) {   // s' 32..63 nonzero only for waves 2,3
        bf16x8_t aP1 = *(const bf16x8_t*)&sw[l16 * 72 + 1 * 32 + quad * 8];
#pragma unroll
        for (int dvt = 0; dvt < 4; ++dvt) {
            bf16x8_t bV1 = *(const bf16x8_t*)(vB + (long)(dvt * 16 + l16) * S_ + 1 * 32 + quad * 8);
            accO[dvt] = __builtin_amdgcn_mfma_f32_16x16x32_bf16(aP1, bV1, accO[dvt], 0, 0, 0);
        }
    }

    // epilogue
#pragma unroll
    for (int dvt = 0; dvt < 4; ++dvt)
#pragma unroll
        for (int r = 0; r < 4; ++r) {
            int row = tch * 64 + w * 16 + quad * 4 + r;
            out[((long)(b * S_ + row)) * 1024 + hh * 64 + dvt * 16 + l16] = accO[dvt][r];
        }
}

extern "C" void kernel_launch(void* const* d_in, const int* in_sizes, int n_in,
                              void* d_out, int out_size, void* d_ws, size_t ws_size,
                              hipStream_t stream) {
    const float* Q = (const float*)d_in[0];
    const float* K = (const float*)d_in[1];
    const float* V = (const float*)d_in[2];
    float* out = (float*)d_out;

    const size_t perBuf = (size_t)B_ * H_ * S_ * D_;   // 4.19M shorts = 8.4 MB
    unsigned short* qb = (unsigned short*)d_ws;
    unsigned short* kb = qb + perBuf;
    unsigned short* vt = kb + perBuf;
    unsigned short* kt = vt + perBuf;
    unsigned short* Sg = kt + perBuf;                  // 32*32*4096 = perBuf shorts

    hipLaunchKernelGGL(prep1_kernel, dim3(1024), dim3(256), 0, stream, Q, K, qb, kb);
    hipLaunchKernelGGL(prep2_kernel, dim3(2048), dim3(256), 0, stream, V, kb, vt, kt);
    hipLaunchKernelGGL(state_kernel, dim3(32),   dim3(256), 0, stream, kt, vt, Sg);
    hipLaunchKernelGGL(outc_kernel,  dim3(1024), dim3(256), 0, stream, qb, kb, vt, Sg, out);
}

// Round 8
// 124.143 us; speedup vs baseline: 1.2688x; 1.2688x over previous
//
#include <hip/hip_runtime.h>
#include <hip/hip_bf16.h>
#include <math.h>

#define B_  2
#define S_  2048
#define H_  16
#define D_  64

typedef __attribute__((ext_vector_type(8))) short bf16x8_t;
typedef __attribute__((ext_vector_type(4))) float f32x4_t;

__device__ __forceinline__ unsigned short f2bf(float f) {
    __hip_bfloat16 h = __float2bfloat16(f);
    return __builtin_bit_cast(unsigned short, h);
}
__device__ __forceinline__ float bf2f(unsigned short u) {
    unsigned int x = ((unsigned int)u) << 16;
    return __builtin_bit_cast(float, x);
}

// ---------------- kernel 1: prep1 — QK rotate+decay (proven) ----------
// 1024 blocks x 256 threads; 4 rows per block; qb/kb keep input layout [b][s][1024].
__global__ __launch_bounds__(256) void prep1_kernel(const float* __restrict__ Q,
                                                    const float* __restrict__ K,
                                                    unsigned short* __restrict__ qb,
                                                    unsigned short* __restrict__ kb) {
    __shared__ float4 rotq[4 * 32];
    __shared__ float  gl[4 * 16 * 2];
    int t   = threadIdx.x;
    int bid = blockIdx.x;

    if (t < 128) {
        int sl = t >> 5, i = t & 31;
        int s  = (bid * 4 + sl) & 2047;
        float pos = (float)s;
        float bsc  = (2.0f * (float)i + 25.6f) / 89.6f;
        float xsc  = exp2f(log2f(bsc) * pos * (1.0f / 512.0f));
        float invf = exp2f(-(float)i * (13.287712379549449f / 32.0f));
        float ang  = pos * invf;
        float kq = rintf(ang * 0.15915494309189535f);
        float rr = fmaf(kq, -6.2831853071795865f, ang);
        float sn = sinf(rr), cs = cosf(rr);
        float rxs = 1.0f / xsc;
        rotq[sl * 32 + i] = make_float4(cs * xsc, sn * xsc, cs * rxs, sn * rxs);
    } else {
        int u  = t - 128;
        int sl = u >> 5, hh = (u >> 1) & 15, pm = u & 1;
        int s  = (bid * 4 + sl) & 2047;
        float lnv = -3.4657359027997265f + (float)hh * (-0.18483924814931874f);
        float l2g = log2f(1.0f - expf(lnv));
        gl[(sl * 16 + hh) * 2 + pm] = exp2f((pm ? -(float)s : (float)s) * l2g);
    }
    __syncthreads();

    int hh = t >> 4, i8 = t & 15;
#pragma unroll
    for (int j = 0; j < 4; ++j) {
        int r = bid * 4 + j;
        float4 r0 = rotq[j * 32 + 2 * i8];
        float4 r1 = rotq[j * 32 + 2 * i8 + 1];
        float gx = gl[(j * 16 + hh) * 2 + 0];
        float gy = gl[(j * 16 + hh) * 2 + 1];

        long idx = (long)r * 1024 + t * 4;
        float4 xq = *(const float4*)(Q + idx);
        float4 xk = *(const float4*)(K + idx);

        float cq0 = r0.x * gx, sq0 = r0.y * gx;
        float ck0 = r0.z * gy, sk0 = r0.w * gy;
        float cq1 = r1.x * gx, sq1 = r1.y * gx;
        float ck1 = r1.z * gy, sk1 = r1.w * gy;

        float q0 = xq.x * cq0 - xq.y * sq0, q1 = xq.y * cq0 + xq.x * sq0;
        float q2 = xq.z * cq1 - xq.w * sq1, q3 = xq.w * cq1 + xq.z * sq1;
        float k0 = xk.x * ck0 - xk.y * sk0, k1 = xk.y * ck0 + xk.x * sk0;
        float k2 = xk.z * ck1 - xk.w * sk1, k3 = xk.w * ck1 + xk.z * sk1;

        *(uint2*)(qb + idx) = make_uint2((unsigned)f2bf(q0) | ((unsigned)f2bf(q1) << 16),
                                         (unsigned)f2bf(q2) | ((unsigned)f2bf(q3) << 16));
        *(uint2*)(kb + idx) = make_uint2((unsigned)f2bf(k0) | ((unsigned)f2bf(k1) << 16),
                                         (unsigned)f2bf(k2) | ((unsigned)f2bf(k3) << 16));
    }
}

// ---------------- kernel 2: prep2 — transposes (V from input fp32; K from kb bf16) ----
// blocks [0,1024):    V-tile -> vt[bh][d][s]   (verbatim proven path)
// blocks [1024,2048): K-tile -> kt[bh][d][s]   (same code, bf16 source)
__global__ __launch_bounds__(256) void prep2_kernel(const float* __restrict__ V,
                                                    const unsigned short* __restrict__ kb,
                                                    unsigned short* __restrict__ vt,
                                                    unsigned short* __restrict__ kt) {
    __shared__ float tile[64 * 65];
    int t   = threadIdx.x;
    int bid = blockIdx.x;
    bool isK = bid >= 1024;
    int vb = isK ? bid - 1024 : bid;
    int bh = vb & 31;
    int b = bh >> 4, hh = bh & 15;
    int s0 = (vb >> 5) * 64;

#pragma unroll
    for (int it = 0; it < 4; ++it) {
        int f  = it * 256 + t;
        int sl = f >> 4;
        int d4 = f & 15;
        long a = ((long)(b * S_ + s0 + sl)) * 1024 + hh * 64 + d4 * 4;
        float f0, f1, f2, f3;
        if (!isK) {
            float4 v = *(const float4*)(V + a);
            f0 = v.x; f1 = v.y; f2 = v.z; f3 = v.w;
        } else {
            uint2 u = *(const uint2*)(kb + a);
            f0 = bf2f((unsigned short)(u.x & 0xffff));
            f1 = bf2f((unsigned short)(u.x >> 16));
            f2 = bf2f((unsigned short)(u.y & 0xffff));
            f3 = bf2f((unsigned short)(u.y >> 16));
        }
        tile[sl * 65 + d4 * 4 + 0] = f0;
        tile[sl * 65 + d4 * 4 + 1] = f1;
        tile[sl * 65 + d4 * 4 + 2] = f2;
        tile[sl * 65 + d4 * 4 + 3] = f3;
    }
    __syncthreads();
    int d = t >> 2, c = t & 3;
    unsigned int pk[8];
#pragma unroll
    for (int jj = 0; jj < 8; ++jj) {
        float f0 = tile[(c * 16 + 2 * jj + 0) * 65 + d];
        float f1 = tile[(c * 16 + 2 * jj + 1) * 65 + d];
        pk[jj] = (unsigned int)f2bf(f0) | ((unsigned int)f2bf(f1) << 16);
    }
    unsigned short* outp = (isK ? kt : vt) + ((long)(bh * 64 + d)) * S_ + s0 + c * 16;
    ((uint4*)outp)[0] = make_uint4(pk[0], pk[1], pk[2], pk[3]);
    ((uint4*)outp)[1] = make_uint4(pk[4], pk[5], pk[6], pk[7]);
}

// ---------------- kernel 3a: gchunk — per-chunk outer products (PARALLEL) -------
// R7 post-mortem: state_kernel was 47.8 us at 1.1% occupancy (32 serial blocks).
// Split: 1024 blocks (bh x chunk) each compute G_j = V^T_j x K_j with the
// IDENTICAL MFMA body that passed inside state_kernel; write bf16 G_j.
__global__ __launch_bounds__(256) void gchunk_kernel(const unsigned short* __restrict__ kt,
                                                     const unsigned short* __restrict__ vt,
                                                     unsigned short* __restrict__ Gg) {
    int t = threadIdx.x;
    int w = t >> 6, lane = t & 63, quad = lane >> 4, l16 = lane & 15;
    int idx = blockIdx.x;
    int bh = idx >> 5, j = idx & 31;          // Gg slot = bh*32 + j = idx
    const unsigned short* ktB = kt + (long)bh * 64 * S_;
    const unsigned short* vtB = vt + (long)bh * 64 * S_;

    f32x4_t accS[4];
#pragma unroll
    for (int dkt = 0; dkt < 4; ++dkt) accS[dkt] = (f32x4_t){0.f, 0.f, 0.f, 0.f};

    bf16x8_t aV[2], bK[4][2];
#pragma unroll
    for (int sst = 0; sst < 2; ++sst)
        aV[sst] = *(const bf16x8_t*)(vtB + (long)(w * 16 + l16) * S_ + j * 64 + sst * 32 + quad * 8);
#pragma unroll
    for (int dkt = 0; dkt < 4; ++dkt)
#pragma unroll
        for (int sst = 0; sst < 2; ++sst)
            bK[dkt][sst] = *(const bf16x8_t*)(ktB + (long)(dkt * 16 + l16) * S_ + j * 64 + sst * 32 + quad * 8);
#pragma unroll
    for (int dkt = 0; dkt < 4; ++dkt)
#pragma unroll
        for (int sst = 0; sst < 2; ++sst)
            accS[dkt] = __builtin_amdgcn_mfma_f32_16x16x32_bf16(aV[sst], bK[dkt][sst], accS[dkt], 0, 0, 0);

    unsigned short* Gp = Gg + (long)idx * 4096;
#pragma unroll
    for (int dkt = 0; dkt < 4; ++dkt)
#pragma unroll
        for (int r = 0; r < 4; ++r)
            Gp[(w * 16 + quad * 4 + r) * 64 + dkt * 16 + l16] = f2bf(accS[dkt][r]);
}

// ---------------- kernel 3b: scan — elementwise prefix over 32 chunks ----------
// 512 blocks x 256 threads: one thread per (bh, element e of 4096). fp32 acc;
// loads independent of the acc chain -> deep ILP; coalesced bf16 access.
// Sg[bh][tch] = sum_{j<tch} G_j  (Sg[bh][0] never written; outc guards tch>0).
__global__ __launch_bounds__(256) void scan_kernel(const unsigned short* __restrict__ Gg,
                                                   unsigned short* __restrict__ Sg) {
    int tid = blockIdx.x * 256 + threadIdx.x;   // 0..131071
    int bh  = tid >> 12;
    int e   = tid & 4095;
    long base = ((long)bh * 32) * 4096 + e;
    float acc = 0.0f;
#pragma unroll
    for (int j = 0; j < 32; ++j) {
        if (j > 0) Sg[base + (long)j * 4096] = f2bf(acc);
        acc += bf2f(Gg[base + (long)j * 4096]);
    }
}

// ---------------- kernel 4: outc — per-(bh,chunk) output (proven R7) -----------
__global__ __launch_bounds__(256) void outc_kernel(const unsigned short* __restrict__ qb,
                                                   const unsigned short* __restrict__ kb,
                                                   const unsigned short* __restrict__ vt,
                                                   const unsigned short* __restrict__ Sg,
                                                   float* __restrict__ out) {
    __shared__ __align__(16) unsigned short strip[4][16 * 72];  // per-wave 16 q x 64 s' (+8 pad)
    int t = threadIdx.x;
    int w = t >> 6, lane = t & 63, quad = lane >> 4, l16 = lane & 15;
    int idx = blockIdx.x;
    int bh  = idx & 31;
    int tch = idx >> 5;           // chunk 0..31
    int b = bh >> 4, hh = bh & 15;

    const unsigned short* qB = qb + ((long)(b * S_ + tch * 64)) * 1024 + hh * 64;
    const unsigned short* kB = kb + ((long)(b * S_ + tch * 64)) * 1024 + hh * 64;
    const unsigned short* vB = vt + (long)bh * 64 * S_ + tch * 64;
    const unsigned short* SB = Sg + ((long)(bh * 32 + tch)) * 4096;

    bf16x8_t aQ[2];
#pragma unroll
    for (int kk = 0; kk < 2; ++kk)
        aQ[kk] = *(const bf16x8_t*)(qB + (long)(w * 16 + l16) * 1024 + kk * 32 + quad * 8);

    f32x4_t accO[4];
#pragma unroll
    for (int dvt = 0; dvt < 4; ++dvt) accO[dvt] = (f32x4_t){0.f, 0.f, 0.f, 0.f};

    // ---- cross-chunk: q-hat x S^T
    if (tch > 0) {
#pragma unroll
        for (int dvt = 0; dvt < 4; ++dvt)
#pragma unroll
            for (int kk = 0; kk < 2; ++kk) {
                bf16x8_t bS = *(const bf16x8_t*)(SB + (dvt * 16 + l16) * 64 + kk * 32 + quad * 8);
                accO[dvt] = __builtin_amdgcn_mfma_f32_16x16x32_bf16(aQ[kk], bS, accO[dvt], 0, 0, 0);
            }
    }

    // ---- diagonal chunk: swapped QK^T, strip, PV
    unsigned short* sw = strip[w];
    for (int st = w + 1; st < 4; ++st)
        *(uint2*)&sw[l16 * 72 + st * 16 + quad * 4] = make_uint2(0u, 0u);

    for (int st = 0; st <= w; ++st) {
        f32x4_t pp = (f32x4_t){0.f, 0.f, 0.f, 0.f};
#pragma unroll
        for (int kk = 0; kk < 2; ++kk) {
            bf16x8_t aK = *(const bf16x8_t*)(kB + (long)(st * 16 + l16) * 1024 + kk * 32 + quad * 8);
            pp = __builtin_amdgcn_mfma_f32_16x16x32_bf16(aK, aQ[kk], pp, 0, 0, 0);
        }
        if (st == w) {
#pragma unroll
            for (int r = 0; r < 4; ++r)
                if (quad * 4 + r > l16) pp[r] = 0.0f;   // keep iff q >= s'
        }
        uint2 pk2;
        pk2.x = (unsigned)f2bf(pp[0]) | ((unsigned)f2bf(pp[1]) << 16);
        pk2.y = (unsigned)f2bf(pp[2]) | ((unsigned)f2bf(pp[3]) << 16);
        *(uint2*)&sw[l16 * 72 + st * 16 + quad * 4] = pk2;
    }

    bf16x8_t aP0 = *(const bf16x8_t*)&sw[l16 * 72 + 0 * 32 + quad * 8];
#pragma unroll
    for (int dvt = 0; dvt < 4; ++dvt) {
        bf16x8_t bV0 = *(const bf16x8_t*)(vB + (long)(dvt * 16 + l16) * S_ + 0 * 32 + quad * 8);
        accO[dvt] = __builtin_amdgcn_mfma_f32_16x16x32_bf16(aP0, bV0, accO[dvt], 0, 0, 0);
    }
    if (w >= 2) {
        bf16x8_t aP1 = *(const bf16x8_t*)&sw[l16 * 72 + 1 * 32 + quad * 8];
#pragma unroll
        for (int dvt = 0; dvt < 4; ++dvt) {
            bf16x8_t bV1 = *(const bf16x8_t*)(vB + (long)(dvt * 16 + l16) * S_ + 1 * 32 + quad * 8);
            accO[dvt] = __builtin_amdgcn_mfma_f32_16x16x32_bf16(aP1, bV1, accO[dvt], 0, 0, 0);
        }
    }

#pragma unroll
    for (int dvt = 0; dvt < 4; ++dvt)
#pragma unroll
        for (int r = 0; r < 4; ++r) {
            int row = tch * 64 + w * 16 + quad * 4 + r;
            out[((long)(b * S_ + row)) * 1024 + hh * 64 + dvt * 16 + l16] = accO[dvt][r];
        }
}

extern "C" void kernel_launch(void* const* d_in, const int* in_sizes, int n_in,
                              void* d_out, int out_size, void* d_ws, size_t ws_size,
                              hipStream_t stream) {
    const float* Q = (const float*)d_in[0];
    const float* K = (const float*)d_in[1];
    const float* V = (const float*)d_in[2];
    float* out = (float*)d_out;

    const size_t perBuf = (size_t)B_ * H_ * S_ * D_;   // 4.19M shorts = 8.4 MB
    unsigned short* qb = (unsigned short*)d_ws;
    unsigned short* kb = qb + perBuf;
    unsigned short* vt = kb + perBuf;
    unsigned short* kt = vt + perBuf;
    unsigned short* Sg = kt + perBuf;                  // 32*32*4096 = perBuf shorts
    unsigned short* Gg = Sg + perBuf;                  // 32*32*4096 = perBuf shorts

    hipLaunchKernelGGL(prep1_kernel,  dim3(1024), dim3(256), 0, stream, Q, K, qb, kb);
    hipLaunchKernelGGL(prep2_kernel,  dim3(2048), dim3(256), 0, stream, V, kb, vt, kt);
    hipLaunchKernelGGL(gchunk_kernel, dim3(1024), dim3(256), 0, stream, kt, vt, Gg);
    hipLaunchKernelGGL(scan_kernel,   dim3(512),  dim3(256), 0, stream, Gg, Sg);
    hipLaunchKernelGGL(outc_kernel,   dim3(1024), dim3(256), 0, stream, qb, kb, vt, Sg, out);
}

// Round 9
// 114.482 us; speedup vs baseline: 1.3759x; 1.0844x over previous
//
#include <hip/hip_runtime.h>
#include <hip/hip_bf16.h>
#include <math.h>

#define B_  2
#define S_  2048
#define H_  16
#define D_  64

typedef __attribute__((ext_vector_type(8))) short bf16x8_t;
typedef __attribute__((ext_vector_type(4))) float f32x4_t;

__device__ __forceinline__ unsigned short f2bf(float f) {
    __hip_bfloat16 h = __float2bfloat16(f);
    return __builtin_bit_cast(unsigned short, h);
}
__device__ __forceinline__ float bf2f(unsigned short u) {
    unsigned int x = ((unsigned int)u) << 16;
    return __builtin_bit_cast(float, x);
}

// ---------------- kernel 1: prep1 — QK rotate+decay (proven R8) ----------
// 1024 blocks x 256 threads; 4 rows per block; qb/kb keep input layout [b][s][1024].
__global__ __launch_bounds__(256) void prep1_kernel(const float* __restrict__ Q,
                                                    const float* __restrict__ K,
                                                    unsigned short* __restrict__ qb,
                                                    unsigned short* __restrict__ kb) {
    __shared__ float4 rotq[4 * 32];
    __shared__ float  gl[4 * 16 * 2];
    int t   = threadIdx.x;
    int bid = blockIdx.x;

    if (t < 128) {
        int sl = t >> 5, i = t & 31;
        int s  = (bid * 4 + sl) & 2047;
        float pos = (float)s;
        float bsc  = (2.0f * (float)i + 25.6f) / 89.6f;
        float xsc  = exp2f(log2f(bsc) * pos * (1.0f / 512.0f));
        float invf = exp2f(-(float)i * (13.287712379549449f / 32.0f));
        float ang  = pos * invf;
        float kq = rintf(ang * 0.15915494309189535f);
        float rr = fmaf(kq, -6.2831853071795865f, ang);
        float sn = sinf(rr), cs = cosf(rr);
        float rxs = 1.0f / xsc;
        rotq[sl * 32 + i] = make_float4(cs * xsc, sn * xsc, cs * rxs, sn * rxs);
    } else {
        int u  = t - 128;
        int sl = u >> 5, hh = (u >> 1) & 15, pm = u & 1;
        int s  = (bid * 4 + sl) & 2047;
        float lnv = -3.4657359027997265f + (float)hh * (-0.18483924814931874f);
        float l2g = log2f(1.0f - expf(lnv));
        gl[(sl * 16 + hh) * 2 + pm] = exp2f((pm ? -(float)s : (float)s) * l2g);
    }
    __syncthreads();

    int hh = t >> 4, i8 = t & 15;
#pragma unroll
    for (int j = 0; j < 4; ++j) {
        int r = bid * 4 + j;
        float4 r0 = rotq[j * 32 + 2 * i8];
        float4 r1 = rotq[j * 32 + 2 * i8 + 1];
        float gx = gl[(j * 16 + hh) * 2 + 0];
        float gy = gl[(j * 16 + hh) * 2 + 1];

        long idx = (long)r * 1024 + t * 4;
        float4 xq = *(const float4*)(Q + idx);
        float4 xk = *(const float4*)(K + idx);

        float cq0 = r0.x * gx, sq0 = r0.y * gx;
        float ck0 = r0.z * gy, sk0 = r0.w * gy;
        float cq1 = r1.x * gx, sq1 = r1.y * gx;
        float ck1 = r1.z * gy, sk1 = r1.w * gy;

        float q0 = xq.x * cq0 - xq.y * sq0, q1 = xq.y * cq0 + xq.x * sq0;
        float q2 = xq.z * cq1 - xq.w * sq1, q3 = xq.w * cq1 + xq.z * sq1;
        float k0 = xk.x * ck0 - xk.y * sk0, k1 = xk.y * ck0 + xk.x * sk0;
        float k2 = xk.z * ck1 - xk.w * sk1, k3 = xk.w * ck1 + xk.z * sk1;

        *(uint2*)(qb + idx) = make_uint2((unsigned)f2bf(q0) | ((unsigned)f2bf(q1) << 16),
                                         (unsigned)f2bf(q2) | ((unsigned)f2bf(q3) << 16));
        *(uint2*)(kb + idx) = make_uint2((unsigned)f2bf(k0) | ((unsigned)f2bf(k1) << 16),
                                         (unsigned)f2bf(k2) | ((unsigned)f2bf(k3) << 16));
    }
}

// ---------------- kernel 2: gchunkT — fused transpose + per-chunk outer product ----
// R9 CHANGE: prep2 folded in. 1024 blocks (bh x chunk j). Stage V-chunk fp32 ->
// LDS (proven prep2 pattern) -> pack V^T into LDS vtile AND global vt (same pk
// regs); restage kb-chunk -> pack K^T into LDS ktile (kt buffer ELIMINATED —
// never touches HBM). Then the identical R8 gchunk MFMA body, fragments read
// from vtile/ktile (same (row, s-offset) semantics, rows padded to 72 shorts).
__global__ __launch_bounds__(256) void gchunkT_kernel(const float* __restrict__ V,
                                                      const unsigned short* __restrict__ kb,
                                                      unsigned short* __restrict__ vt,
                                                      unsigned short* __restrict__ Gg) {
    __shared__ float tileF[64 * 65];                       // fp32 staging (V, then K)
    __shared__ __align__(16) unsigned short vtile[64 * 72];
    __shared__ __align__(16) unsigned short ktile[64 * 72];
    int t = threadIdx.x;
    int idx = blockIdx.x;
    int bh = idx >> 5, j = idx & 31;
    int b = bh >> 4, hh = bh & 15;
    int s0 = j * 64;
    int d = t >> 2, c = t & 3;

    // ---- stage V chunk (fp32) -> tileF [proven prep2 pattern]
#pragma unroll
    for (int it = 0; it < 4; ++it) {
        int f  = it * 256 + t;
        int sl = f >> 4, d4 = f & 15;
        float4 v = *(const float4*)(V + ((long)(b * S_ + s0 + sl)) * 1024 + hh * 64 + d4 * 4);
        tileF[sl * 65 + d4 * 4 + 0] = v.x;
        tileF[sl * 65 + d4 * 4 + 1] = v.y;
        tileF[sl * 65 + d4 * 4 + 2] = v.z;
        tileF[sl * 65 + d4 * 4 + 3] = v.w;
    }
    __syncthreads();
    // ---- pack V^T row d, s-cols c*16..+15 -> vtile + global vt [proven pack]
    {
        unsigned int pk[8];
#pragma unroll
        for (int jj = 0; jj < 8; ++jj) {
            float f0 = tileF[(c * 16 + 2 * jj + 0) * 65 + d];
            float f1 = tileF[(c * 16 + 2 * jj + 1) * 65 + d];
            pk[jj] = (unsigned int)f2bf(f0) | ((unsigned int)f2bf(f1) << 16);
        }
        uint4 u0 = make_uint4(pk[0], pk[1], pk[2], pk[3]);
        uint4 u1 = make_uint4(pk[4], pk[5], pk[6], pk[7]);
        ((uint4*)&vtile[d * 72 + c * 16])[0] = u0;
        ((uint4*)&vtile[d * 72 + c * 16 + 8])[0] = u1;
        unsigned short* outp = vt + ((long)(bh * 64 + d)) * S_ + s0 + c * 16;
        ((uint4*)outp)[0] = u0;
        ((uint4*)outp)[1] = u1;
    }
    __syncthreads();   // tileF free
    // ---- stage kb chunk (bf16 -> fp32) -> tileF [proven prep2-isK pattern]
#pragma unroll
    for (int it = 0; it < 4; ++it) {
        int f  = it * 256 + t;
        int sl = f >> 4, d4 = f & 15;
        uint2 u = *(const uint2*)(kb + ((long)(b * S_ + s0 + sl)) * 1024 + hh * 64 + d4 * 4);
        tileF[sl * 65 + d4 * 4 + 0] = bf2f((unsigned short)(u.x & 0xffff));
        tileF[sl * 65 + d4 * 4 + 1] = bf2f((unsigned short)(u.x >> 16));
        tileF[sl * 65 + d4 * 4 + 2] = bf2f((unsigned short)(u.y & 0xffff));
        tileF[sl * 65 + d4 * 4 + 3] = bf2f((unsigned short)(u.y >> 16));
    }
    __syncthreads();
    // ---- pack K^T -> ktile (LDS only)
    {
        unsigned int pk[8];
#pragma unroll
        for (int jj = 0; jj < 8; ++jj) {
            float f0 = tileF[(c * 16 + 2 * jj + 0) * 65 + d];
            float f1 = tileF[(c * 16 + 2 * jj + 1) * 65 + d];
            pk[jj] = (unsigned int)f2bf(f0) | ((unsigned int)f2bf(f1) << 16);
        }
        ((uint4*)&ktile[d * 72 + c * 16])[0] = make_uint4(pk[0], pk[1], pk[2], pk[3]);
        ((uint4*)&ktile[d * 72 + c * 16 + 8])[0] = make_uint4(pk[4], pk[5], pk[6], pk[7]);
    }
    __syncthreads();

    // ---- G = V^T x K  [identical R8 gchunk MFMA body, LDS-local fragments]
    int w = t >> 6, lane = t & 63, quad = lane >> 4, l16 = lane & 15;
    f32x4_t accS[4];
#pragma unroll
    for (int dkt = 0; dkt < 4; ++dkt) accS[dkt] = (f32x4_t){0.f, 0.f, 0.f, 0.f};

    bf16x8_t aV[2], bK[4][2];
#pragma unroll
    for (int sst = 0; sst < 2; ++sst)
        aV[sst] = *(const bf16x8_t*)&vtile[(w * 16 + l16) * 72 + sst * 32 + quad * 8];
#pragma unroll
    for (int dkt = 0; dkt < 4; ++dkt)
#pragma unroll
        for (int sst = 0; sst < 2; ++sst)
            bK[dkt][sst] = *(const bf16x8_t*)&ktile[(dkt * 16 + l16) * 72 + sst * 32 + quad * 8];
#pragma unroll
    for (int dkt = 0; dkt < 4; ++dkt)
#pragma unroll
        for (int sst = 0; sst < 2; ++sst)
            accS[dkt] = __builtin_amdgcn_mfma_f32_16x16x32_bf16(aV[sst], bK[dkt][sst], accS[dkt], 0, 0, 0);

    unsigned short* Gp = Gg + (long)idx * 4096;
#pragma unroll
    for (int dkt = 0; dkt < 4; ++dkt)
#pragma unroll
        for (int r = 0; r < 4; ++r)
            Gp[(w * 16 + quad * 4 + r) * 64 + dkt * 16 + l16] = f2bf(accS[dkt][r]);
}

// ---------------- kernel 3: scan — elementwise prefix over 32 chunks (proven R8) ----
__global__ __launch_bounds__(256) void scan_kernel(const unsigned short* __restrict__ Gg,
                                                   unsigned short* __restrict__ Sg) {
    int tid = blockIdx.x * 256 + threadIdx.x;   // 0..131071
    int bh  = tid >> 12;
    int e   = tid & 4095;
    long base = ((long)bh * 32) * 4096 + e;
    float acc = 0.0f;
#pragma unroll
    for (int j = 0; j < 32; ++j) {
        if (j > 0) Sg[base + (long)j * 4096] = f2bf(acc);
        acc += bf2f(Gg[base + (long)j * 4096]);
    }
}

// ---------------- kernel 4: outc — per-(bh,chunk) output (proven R8) -----------
__global__ __launch_bounds__(256) void outc_kernel(const unsigned short* __restrict__ qb,
                                                   const unsigned short* __restrict__ kb,
                                                   const unsigned short* __restrict__ vt,
                                                   const unsigned short* __restrict__ Sg,
                                                   float* __restrict__ out) {
    __shared__ __align__(16) unsigned short strip[4][16 * 72];  // per-wave 16 q x 64 s' (+8 pad)
    int t = threadIdx.x;
    int w = t >> 6, lane = t & 63, quad = lane >> 4, l16 = lane & 15;
    int idx = blockIdx.x;
    int bh  = idx & 31;
    int tch = idx >> 5;           // chunk 0..31
    int b = bh >> 4, hh = bh & 15;

    const unsigned short* qB = qb + ((long)(b * S_ + tch * 64)) * 1024 + hh * 64;
    const unsigned short* kB = kb + ((long)(b * S_ + tch * 64)) * 1024 + hh * 64;
    const unsigned short* vB = vt + (long)bh * 64 * S_ + tch * 64;
    const unsigned short* SB = Sg + ((long)(bh * 32 + tch)) * 4096;

    bf16x8_t aQ[2];
#pragma unroll
    for (int kk = 0; kk < 2; ++kk)
        aQ[kk] = *(const bf16x8_t*)(qB + (long)(w * 16 + l16) * 1024 + kk * 32 + quad * 8);

    f32x4_t accO[4];
#pragma unroll
    for (int dvt = 0; dvt < 4; ++dvt) accO[dvt] = (f32x4_t){0.f, 0.f, 0.f, 0.f};

    // ---- cross-chunk: q-hat x S^T
    if (tch > 0) {
#pragma unroll
        for (int dvt = 0; dvt < 4; ++dvt)
#pragma unroll
            for (int kk = 0; kk < 2; ++kk) {
                bf16x8_t bS = *(const bf16x8_t*)(SB + (dvt * 16 + l16) * 64 + kk * 32 + quad * 8);
                accO[dvt] = __builtin_amdgcn_mfma_f32_16x16x32_bf16(aQ[kk], bS, accO[dvt], 0, 0, 0);
            }
    }

    // ---- diagonal chunk: swapped QK^T, strip, PV
    unsigned short* sw = strip[w];
    for (int st = w + 1; st < 4; ++st)
        *(uint2*)&sw[l16 * 72 + st * 16 + quad * 4] = make_uint2(0u, 0u);

    for (int st = 0; st <= w; ++st) {
        f32x4_t pp = (f32x4_t){0.f, 0.f, 0.f, 0.f};
#pragma unroll
        for (int kk = 0; kk < 2; ++kk) {
            bf16x8_t aK = *(const bf16x8_t*)(kB + (long)(st * 16 + l16) * 1024 + kk * 32 + quad * 8);
            pp = __builtin_amdgcn_mfma_f32_16x16x32_bf16(aK, aQ[kk], pp, 0, 0, 0);
        }
        if (st == w) {
#pragma unroll
            for (int r = 0; r < 4; ++r)
                if (quad * 4 + r > l16) pp[r] = 0.0f;   // keep iff q >= s'
        }
        uint2 pk2;
        pk2.x = (unsigned)f2bf(pp[0]) | ((unsigned)f2bf(pp[1]) << 16);
        pk2.y = (unsigned)f2bf(pp[2]) | ((unsigned)f2bf(pp[3]) << 16);
        *(uint2*)&sw[l16 * 72 + st * 16 + quad * 4] = pk2;
    }

    bf16x8_t aP0 = *(const bf16x8_t*)&sw[l16 * 72 + 0 * 32 + quad * 8];
#pragma unroll
    for (int dvt = 0; dvt < 4; ++dvt) {
        bf16x8_t bV0 = *(const bf16x8_t*)(vB + (long)(dvt * 16 + l16) * S_ + 0 * 32 + quad * 8);
        accO[dvt] = __builtin_amdgcn_mfma_f32_16x16x32_bf16(aP0, bV0, accO[dvt], 0, 0, 0);
    }
    if (w >= 2) {
        bf16x8_t aP1 = *(const bf16x8_t*)&sw[l16 * 72 + 1 * 32 + quad * 8];
#pragma unroll
        for (int dvt = 0; dvt < 4; ++dvt) {
            bf16x8_t bV1 = *(const bf16x8_t*)(vB + (long)(dvt * 16 + l16) * S_ + 1 * 32 + quad * 8);
            accO[dvt] = __builtin_amdgcn_mfma_f32_16x16x32_bf16(aP1, bV1, accO[dvt], 0, 0, 0);
        }
    }

#pragma unroll
    for (int dvt = 0; dvt < 4; ++dvt)
#pragma unroll
        for (int r = 0; r < 4; ++r) {
            int row = tch * 64 + w * 16 + quad * 4 + r;
            out[((long)(b * S_ + row)) * 1024 + hh * 64 + dvt * 16 + l16] = accO[dvt][r];
        }
}

extern "C" void kernel_launch(void* const* d_in, const int* in_sizes, int n_in,
                              void* d_out, int out_size, void* d_ws, size_t ws_size,
                              hipStream_t stream) {
    const float* Q = (const float*)d_in[0];
    const float* K = (const float*)d_in[1];
    const float* V = (const float*)d_in[2];
    float* out = (float*)d_out;

    const size_t perBuf = (size_t)B_ * H_ * S_ * D_;   // 4.19M shorts = 8.4 MB
    unsigned short* qb = (unsigned short*)d_ws;
    unsigned short* kb = qb + perBuf;
    unsigned short* vt = kb + perBuf;
    unsigned short* Sg = vt + perBuf;                  // 32*32*4096 = perBuf shorts
    unsigned short* Gg = Sg + perBuf;                  // 32*32*4096 = perBuf shorts

    hipLaunchKernelGGL(prep1_kernel,   dim3(1024), dim3(256), 0, stream, Q, K, qb, kb);
    hipLaunchKernelGGL(gchunkT_kernel, dim3(1024), dim3(256), 0, stream, V, kb, vt, Gg);
    hipLaunchKernelGGL(scan_kernel,    dim3(512),  dim3(256), 0, stream, Gg, Sg);
    hipLaunchKernelGGL(outc_kernel,    dim3(1024), dim3(256), 0, stream, qb, kb, vt, Sg, out);
}

// Round 10
// 111.229 us; speedup vs baseline: 1.4161x; 1.0292x over previous
//
#include <hip/hip_runtime.h>
#include <hip/hip_bf16.h>
#include <math.h>

#define B_  2
#define S_  2048
#define H_  16
#define D_  64

typedef __attribute__((ext_vector_type(8))) short bf16x8_t;
typedef __attribute__((ext_vector_type(4))) float f32x4_t;

__device__ __forceinline__ unsigned short f2bf(float f) {
    __hip_bfloat16 h = __float2bfloat16(f);
    return __builtin_bit_cast(unsigned short, h);
}
__device__ __forceinline__ float bf2f(unsigned short u) {
    unsigned int x = ((unsigned int)u) << 16;
    return __builtin_bit_cast(float, x);
}

// xPos rotation factors for pair index i (0..31) at position pos: cos, sin (scaled).
// Exact op sequence of the proven prep1 chain.
__device__ __forceinline__ void rotpair(int i, float pos, float& cs_s, float& sn_s, bool down) {
    float bsc  = (2.0f * (float)i + 25.6f) / 89.6f;
    float xsc  = exp2f(log2f(bsc) * pos * (1.0f / 512.0f));
    float invf = exp2f(-(float)i * (13.287712379549449f / 32.0f));
    float ang  = pos * invf;
    float kq = rintf(ang * 0.15915494309189535f);
    float rr = fmaf(kq, -6.2831853071795865f, ang);
    float sn = sinf(rr), cs = cosf(rr);
    float sc = down ? (1.0f / xsc) : xsc;
    cs_s = cs * sc; sn_s = sn * sc;
}

// ---------------- kernel 1: gkv — fused K-rotation + transposes + per-chunk G ----
// R10 CHANGE: prep1 folded in. 1024 blocks (bh x chunk j).
// Stage V fp32 -> tileF -> pack V^T -> vtile + global vt (proven R9).
// Stage K fp32 with INLINE rotation+decay (2 chains per (sl,d4) thread-slot;
// no table, no extra LDS) -> tileF (fp32 k-hat) + global kb (bf16, for outc diag).
// Pack K^T -> ktile; then the identical R8/R9 MFMA body -> Gg. qb is never made.
__global__ __launch_bounds__(256) void gkv_kernel(const float* __restrict__ K,
                                                  const float* __restrict__ V,
                                                  unsigned short* __restrict__ kb,
                                                  unsigned short* __restrict__ vt,
                                                  unsigned short* __restrict__ Gg) {
    __shared__ float tileF[64 * 65];
    __shared__ __align__(16) unsigned short vtile[64 * 72];
    __shared__ __align__(16) unsigned short ktile[64 * 72];
    int t = threadIdx.x;
    int idx = blockIdx.x;
    int bh = idx >> 5, j = idx & 31;
    int b = bh >> 4, hh = bh & 15;
    int s0 = j * 64;
    int d = t >> 2, c = t & 3;

    float lnv = -3.4657359027997265f + (float)hh * (-0.18483924814931874f);
    float l2g = log2f(1.0f - expf(lnv));

    // ---- stage V chunk (fp32) -> tileF [proven]
#pragma unroll
    for (int it = 0; it < 4; ++it) {
        int f  = it * 256 + t;
        int sl = f >> 4, d4 = f & 15;
        float4 v = *(const float4*)(V + ((long)(b * S_ + s0 + sl)) * 1024 + hh * 64 + d4 * 4);
        tileF[sl * 65 + d4 * 4 + 0] = v.x;
        tileF[sl * 65 + d4 * 4 + 1] = v.y;
        tileF[sl * 65 + d4 * 4 + 2] = v.z;
        tileF[sl * 65 + d4 * 4 + 3] = v.w;
    }
    __syncthreads();
    // ---- pack V^T -> vtile + global vt [proven]
    {
        unsigned int pk[8];
#pragma unroll
        for (int jj = 0; jj < 8; ++jj) {
            float f0 = tileF[(c * 16 + 2 * jj + 0) * 65 + d];
            float f1 = tileF[(c * 16 + 2 * jj + 1) * 65 + d];
            pk[jj] = (unsigned int)f2bf(f0) | ((unsigned int)f2bf(f1) << 16);
        }
        uint4 u0 = make_uint4(pk[0], pk[1], pk[2], pk[3]);
        uint4 u1 = make_uint4(pk[4], pk[5], pk[6], pk[7]);
        ((uint4*)&vtile[d * 72 + c * 16])[0] = u0;
        ((uint4*)&vtile[d * 72 + c * 16 + 8])[0] = u1;
        unsigned short* outp = vt + ((long)(bh * 64 + d)) * S_ + s0 + c * 16;
        ((uint4*)outp)[0] = u0;
        ((uint4*)outp)[1] = u1;
    }
    __syncthreads();   // tileF free
    // ---- stage K fp32, rotate+decay INLINE -> tileF (fp32 k-hat) + kb (bf16)
#pragma unroll
    for (int it = 0; it < 4; ++it) {
        int f  = it * 256 + t;
        int sl = f >> 4, d4 = f & 15;
        float pos = (float)(s0 + sl);
        long a = ((long)(b * S_ + s0 + sl)) * 1024 + hh * 64 + d4 * 4;
        float4 xk = *(const float4*)(K + a);
        float gsi = exp2f(-pos * l2g);
        float c0, s0f, c1, s1f;
        rotpair(2 * d4 + 0, pos, c0, s0f, true);
        rotpair(2 * d4 + 1, pos, c1, s1f, true);
        float ck0 = c0 * gsi, sk0 = s0f * gsi;
        float ck1 = c1 * gsi, sk1 = s1f * gsi;
        float k0 = xk.x * ck0 - xk.y * sk0, k1 = xk.y * ck0 + xk.x * sk0;
        float k2 = xk.z * ck1 - xk.w * sk1, k3 = xk.w * ck1 + xk.z * sk1;
        tileF[sl * 65 + d4 * 4 + 0] = k0;
        tileF[sl * 65 + d4 * 4 + 1] = k1;
        tileF[sl * 65 + d4 * 4 + 2] = k2;
        tileF[sl * 65 + d4 * 4 + 3] = k3;
        *(uint2*)(kb + a) = make_uint2((unsigned)f2bf(k0) | ((unsigned)f2bf(k1) << 16),
                                       (unsigned)f2bf(k2) | ((unsigned)f2bf(k3) << 16));
    }
    __syncthreads();
    // ---- pack K^T -> ktile (LDS only) [proven]
    {
        unsigned int pk[8];
#pragma unroll
        for (int jj = 0; jj < 8; ++jj) {
            float f0 = tileF[(c * 16 + 2 * jj + 0) * 65 + d];
            float f1 = tileF[(c * 16 + 2 * jj + 1) * 65 + d];
            pk[jj] = (unsigned int)f2bf(f0) | ((unsigned int)f2bf(f1) << 16);
        }
        ((uint4*)&ktile[d * 72 + c * 16])[0] = make_uint4(pk[0], pk[1], pk[2], pk[3]);
        ((uint4*)&ktile[d * 72 + c * 16 + 8])[0] = make_uint4(pk[4], pk[5], pk[6], pk[7]);
    }
    __syncthreads();

    // ---- G = V^T x K  [identical R8/R9 MFMA body]
    int w = t >> 6, lane = t & 63, quad = lane >> 4, l16 = lane & 15;
    f32x4_t accS[4];
#pragma unroll
    for (int dkt = 0; dkt < 4; ++dkt) accS[dkt] = (f32x4_t){0.f, 0.f, 0.f, 0.f};

    bf16x8_t aV[2], bK[4][2];
#pragma unroll
    for (int sst = 0; sst < 2; ++sst)
        aV[sst] = *(const bf16x8_t*)&vtile[(w * 16 + l16) * 72 + sst * 32 + quad * 8];
#pragma unroll
    for (int dkt = 0; dkt < 4; ++dkt)
#pragma unroll
        for (int sst = 0; sst < 2; ++sst)
            bK[dkt][sst] = *(const bf16x8_t*)&ktile[(dkt * 16 + l16) * 72 + sst * 32 + quad * 8];
#pragma unroll
    for (int dkt = 0; dkt < 4; ++dkt)
#pragma unroll
        for (int sst = 0; sst < 2; ++sst)
            accS[dkt] = __builtin_amdgcn_mfma_f32_16x16x32_bf16(aV[sst], bK[dkt][sst], accS[dkt], 0, 0, 0);

    unsigned short* Gp = Gg + (long)idx * 4096;
#pragma unroll
    for (int dkt = 0; dkt < 4; ++dkt)
#pragma unroll
        for (int r = 0; r < 4; ++r)
            Gp[(w * 16 + quad * 4 + r) * 64 + dkt * 16 + l16] = f2bf(accS[dkt][r]);
}

// ---------------- kernel 2: scan — elementwise prefix over 32 chunks (proven R8) ----
__global__ __launch_bounds__(256) void scan_kernel(const unsigned short* __restrict__ Gg,
                                                   unsigned short* __restrict__ Sg) {
    int tid = blockIdx.x * 256 + threadIdx.x;   // 0..131071
    int bh  = tid >> 12;
    int e   = tid & 4095;
    long base = ((long)bh * 32) * 4096 + e;
    float acc = 0.0f;
#pragma unroll
    for (int j = 0; j < 32; ++j) {
        if (j > 0) Sg[base + (long)j * 4096] = f2bf(acc);
        acc += bf2f(Gg[base + (long)j * 4096]);
    }
}

// ---------------- kernel 3: outc — per-(bh,chunk) output, Q-rotation inline ------
// R10 CHANGE: aQ fragments built from Q fp32 + inline rotation (4 pairs per
// fragment, unrolled -> static register indexing). qb eliminated. Diag still
// reads kb (written by gkv). Cross/diag/PV bodies verbatim R8/R9.
__global__ __launch_bounds__(256) void outc_kernel(const float* __restrict__ Q,
                                                   const unsigned short* __restrict__ kb,
                                                   const unsigned short* __restrict__ vt,
                                                   const unsigned short* __restrict__ Sg,
                                                   float* __restrict__ out) {
    __shared__ __align__(16) unsigned short strip[4][16 * 72];  // per-wave 16 q x 64 s' (+8 pad)
    int t = threadIdx.x;
    int w = t >> 6, lane = t & 63, quad = lane >> 4, l16 = lane & 15;
    int idx = blockIdx.x;
    int bh  = idx & 31;
    int tch = idx >> 5;           // chunk 0..31
    int b = bh >> 4, hh = bh & 15;

    const unsigned short* kB = kb + ((long)(b * S_ + tch * 64)) * 1024 + hh * 64;
    const unsigned short* vB = vt + (long)bh * 64 * S_ + tch * 64;
    const unsigned short* SB = Sg + ((long)(bh * 32 + tch)) * 4096;

    // ---- build aQ fragments from Q fp32 + inline rotation+decay
    float lnv = -3.4657359027997265f + (float)hh * (-0.18483924814931874f);
    float l2g = log2f(1.0f - expf(lnv));
    int qrow = w * 16 + l16;
    float pos = (float)(tch * 64 + qrow);
    float gs = exp2f(pos * l2g);
    const float* Qp = Q + ((long)(b * S_ + tch * 64 + qrow)) * 1024 + hh * 64;

    bf16x8_t aQ[2];
#pragma unroll
    for (int kk = 0; kk < 2; ++kk) {
        int d0 = kk * 32 + quad * 8;
        float4 x0 = *(const float4*)(Qp + d0);
        float4 x1 = *(const float4*)(Qp + d0 + 4);
        float xs0 = x0.x, xs1 = x0.y, xs2 = x0.z, xs3 = x0.w;
        float xs4 = x1.x, xs5 = x1.y, xs6 = x1.z, xs7 = x1.w;
        bf16x8_t q;
#pragma unroll
        for (int p = 0; p < 4; ++p) {
            float cv, sv;
            rotpair(d0 / 2 + p, pos, cv, sv, false);
            float cq = cv * gs, sq = sv * gs;
            float xe = (p == 0) ? xs0 : (p == 1) ? xs2 : (p == 2) ? xs4 : xs6;
            float xo = (p == 0) ? xs1 : (p == 1) ? xs3 : (p == 2) ? xs5 : xs7;
            q[2 * p]     = (short)f2bf(xe * cq - xo * sq);
            q[2 * p + 1] = (short)f2bf(xo * cq + xe * sq);
        }
        aQ[kk] = q;
    }

    f32x4_t accO[4];
#pragma unroll
    for (int dvt = 0; dvt < 4; ++dvt) accO[dvt] = (f32x4_t){0.f, 0.f, 0.f, 0.f};

    // ---- cross-chunk: q-hat x S^T
    if (tch > 0) {
#pragma unroll
        for (int dvt = 0; dvt < 4; ++dvt)
#pragma unroll
            for (int kk = 0; kk < 2; ++kk) {
                bf16x8_t bS = *(const bf16x8_t*)(SB + (dvt * 16 + l16) * 64 + kk * 32 + quad * 8);
                accO[dvt] = __builtin_amdgcn_mfma_f32_16x16x32_bf16(aQ[kk], bS, accO[dvt], 0, 0, 0);
            }
    }

    // ---- diagonal chunk: swapped QK^T, strip, PV [verbatim]
    unsigned short* sw = strip[w];
    for (int st = w + 1; st < 4; ++st)
        *(uint2*)&sw[l16 * 72 + st * 16 + quad * 4] = make_uint2(0u, 0u);

    for (int st = 0; st <= w; ++st) {
        f32x4_t pp = (f32x4_t){0.f, 0.f, 0.f, 0.f};
#pragma unroll
        for (int kk = 0; kk < 2; ++kk) {
            bf16x8_t aK = *(const bf16x8_t*)(kB + (long)(st * 16 + l16) * 1024 + kk * 32 + quad * 8);
            pp = __builtin_amdgcn_mfma_f32_16x16x32_bf16(aK, aQ[kk], pp, 0, 0, 0);
        }
        if (st == w) {
#pragma unroll
            for (int r = 0; r < 4; ++r)
                if (quad * 4 + r > l16) pp[r] = 0.0f;   // keep iff q >= s'
        }
        uint2 pk2;
        pk2.x = (unsigned)f2bf(pp[0]) | ((unsigned)f2bf(pp[1]) << 16);
        pk2.y = (unsigned)f2bf(pp[2]) | ((unsigned)f2bf(pp[3]) << 16);
        *(uint2*)&sw[l16 * 72 + st * 16 + quad * 4] = pk2;
    }

    bf16x8_t aP0 = *(const bf16x8_t*)&sw[l16 * 72 + 0 * 32 + quad * 8];
#pragma unroll
    for (int dvt = 0; dvt < 4; ++dvt) {
        bf16x8_t bV0 = *(const bf16x8_t*)(vB + (long)(dvt * 16 + l16) * S_ + 0 * 32 + quad * 8);
        accO[dvt] = __builtin_amdgcn_mfma_f32_16x16x32_bf16(aP0, bV0, accO[dvt], 0, 0, 0);
    }
    if (w >= 2) {
        bf16x8_t aP1 = *(const bf16x8_t*)&sw[l16 * 72 + 1 * 32 + quad * 8];
#pragma unroll
        for (int dvt = 0; dvt < 4; ++dvt) {
            bf16x8_t bV1 = *(const bf16x8_t*)(vB + (long)(dvt * 16 + l16) * S_ + 1 * 32 + quad * 8);
            accO[dvt] = __builtin_amdgcn_mfma_f32_16x16x32_bf16(aP1, bV1, accO[dvt], 0, 0, 0);
        }
    }

#pragma unroll
    for (int dvt = 0; dvt < 4; ++dvt)
#pragma unroll
        for (int r = 0; r < 4; ++r) {
            int row = tch * 64 + w * 16 + quad * 4 + r;
            out[((long)(b * S_ + row)) * 1024 + hh * 64 + dvt * 16 + l16] = accO[dvt][r];
        }
}

extern "C" void kernel_launch(void* const* d_in, const int* in_sizes, int n_in,
                              void* d_out, int out_size, void* d_ws, size_t ws_size,
                              hipStream_t stream) {
    const float* Q = (const float*)d_in[0];
    const float* K = (const float*)d_in[1];
    const float* V = (const float*)d_in[2];
    float* out = (float*)d_out;

    const size_t perBuf = (size_t)B_ * H_ * S_ * D_;   // 4.19M shorts = 8.4 MB
    unsigned short* kb = (unsigned short*)d_ws;
    unsigned short* vt = kb + perBuf;
    unsigned short* Sg = vt + perBuf;
    unsigned short* Gg = Sg + perBuf;

    hipLaunchKernelGGL(gkv_kernel,  dim3(1024), dim3(256), 0, stream, K, V, kb, vt, Gg);
    hipLaunchKernelGGL(scan_kernel, dim3(512),  dim3(256), 0, stream, Gg, Sg);
    hipLaunchKernelGGL(outc_kernel, dim3(1024), dim3(256), 0, stream, Q, kb, vt, Sg, out);
}